// Round 5
// baseline (294.527 us; speedup 1.0000x reference)
//
#include <hip/hip_runtime.h>
#include <hip/hip_bf16.h>
#include <stdint.h>

#define DIM 256

typedef float f32x4 __attribute__((ext_vector_type(4)));
typedef short bf16x8 __attribute__((ext_vector_type(8)));
typedef short bf16x4 __attribute__((ext_vector_type(4)));
typedef int   i32x4 __attribute__((ext_vector_type(4)));

__device__ __forceinline__ unsigned short f2bf(float f) {
  union { float f; uint32_t u; } v; v.f = f;
  uint32_t u = v.u;
  u += 0x7FFFu + ((u >> 16) & 1u);   // round-to-nearest-even
  return (unsigned short)(u >> 16);
}

// ---- fused: W transpose/cast (blocks 0..47) + x column partial sums ----
__global__ __launch_bounds__(256) void k_misc(const float* __restrict__ Wq,
    const float* __restrict__ Wk, const float* __restrict__ Wv,
    unsigned short* __restrict__ Wt, const float* __restrict__ x,
    float* __restrict__ partial, int n) {
  if (blockIdx.x < 48) {
    const int w = blockIdx.x >> 4;
    const int nb = blockIdx.x & 15;
    const float* W = (w == 0) ? Wq : (w == 1) ? Wk : Wv;
    unsigned short* dst = Wt + w * DIM * DIM;
    const int row = nb * 16 + (threadIdx.x >> 4);
    const int k0 = (threadIdx.x & 15) * 16;
    for (int k = 0; k < 16; ++k)
      dst[row * DIM + k0 + k] = f2bf(W[(k0 + k) * DIM + row]);
  } else {
    const int b = blockIdx.x - 48, tid = threadIdx.x;
    float acc = 0.f;
    const float* xp = x + (size_t)b * 128 * DIM + tid;
    for (int r = 0; r < 128; ++r) acc += xp[r * DIM];
    partial[b * DIM + tid] = acc;
  }
}

// ---- projections: Q = (x@Wq)/16, K = x@Wk, Vt = (x@Wv)^T, all bf16 ----
__global__ __launch_bounds__(256) void k_proj(const float* __restrict__ x,
    const unsigned short* __restrict__ Wt, unsigned short* __restrict__ Q,
    unsigned short* __restrict__ K, unsigned short* __restrict__ Vt, int n) {
  const int rb = blockIdx.x * 64;
  const int w = blockIdx.y;
  const int wave = threadIdx.x >> 6;
  const int lane = threadIdx.x & 63;
  const int g = lane >> 4;
  const int c = lane & 15;
  const int row0 = rb + wave * 16;

  bf16x8 af[8];
  const float* xp = x + (size_t)(row0 + c) * DIM;
#pragma unroll
  for (int kc = 0; kc < 8; ++kc) {
    f32x4 a0 = *(const f32x4*)(xp + kc * 32 + g * 8);
    f32x4 a1 = *(const f32x4*)(xp + kc * 32 + g * 8 + 4);
    bf16x8 a;
    a[0] = (short)f2bf(a0[0]); a[1] = (short)f2bf(a0[1]);
    a[2] = (short)f2bf(a0[2]); a[3] = (short)f2bf(a0[3]);
    a[4] = (short)f2bf(a1[0]); a[5] = (short)f2bf(a1[1]);
    a[6] = (short)f2bf(a1[2]); a[7] = (short)f2bf(a1[3]);
    af[kc] = a;
  }
  const unsigned short* Wb = Wt + w * DIM * DIM;
  f32x4 acc[16];
#pragma unroll
  for (int t = 0; t < 16; ++t) acc[t] = (f32x4){0.f, 0.f, 0.f, 0.f};
#pragma unroll
  for (int nt = 0; nt < 16; ++nt) {
#pragma unroll
    for (int kc = 0; kc < 8; ++kc) {
      bf16x8 b = *(const bf16x8*)(Wb + (nt * 16 + c) * DIM + kc * 32 + g * 8);
      acc[nt] = __builtin_amdgcn_mfma_f32_16x16x32_bf16(af[kc], b, acc[nt], 0, 0, 0);
    }
  }
  if (w == 2) {
    // Vt: pack 4 consecutive rows (4g..4g+3) into one 8B store per nt
#pragma unroll
    for (int nt = 0; nt < 16; ++nt) {
      const int col = nt * 16 + c;
      bf16x4 pv;
      pv[0] = (short)f2bf(acc[nt][0]); pv[1] = (short)f2bf(acc[nt][1]);
      pv[2] = (short)f2bf(acc[nt][2]); pv[3] = (short)f2bf(acc[nt][3]);
      *(bf16x4*)(Vt + (size_t)col * n + row0 + 4 * g) = pv;
    }
  } else {
#pragma unroll
    for (int nt = 0; nt < 16; ++nt) {
#pragma unroll
      for (int r = 0; r < 4; ++r) {
        const int row = row0 + 4 * g + r;
        const int col = nt * 16 + c;
        const float v = acc[nt][r];
        if (w == 0) Q[(size_t)row * DIM + col] = f2bf(v * 0.0625f);
        else        K[(size_t)row * DIM + col] = f2bf(v);
      }
    }
  }
}

// ---- row 0 exact path for fallback: out[0] = mean_n(x) @ Wv ----
__global__ void k_meanB(const float* __restrict__ partial, const float* __restrict__ Wv,
                        float* __restrict__ out, int n) {
  __shared__ float xm[DIM];
  const int tid = threadIdx.x;
  float acc = 0.f;
  const int nb = n / 128;
  for (int b = 0; b < nb; ++b) acc += partial[b * DIM + tid];
  xm[tid] = acc / (float)n;
  __syncthreads();
  float o = 0.f;
  for (int k = 0; k < DIM; ++k) o += xm[k] * Wv[k * DIM + tid];
  out[tid] = o;
}

// ---- fallback flash (round-2): 8 waves key-split one 16-row tile ----
__global__ __launch_bounds__(512, 4) void k_flash2(const unsigned short* __restrict__ Q,
    const unsigned short* __restrict__ K, const unsigned short* __restrict__ Vt,
    float* __restrict__ out, int n) {
  __shared__ float so[4][16][257];
  __shared__ float sml[4][2][16];
  __shared__ unsigned short plds[8][16][40];

  const int wave = threadIdx.x >> 6;
  const int lane = threadIdx.x & 63;
  const int g = lane >> 4;
  const int c = lane & 15;
  const int ntiles = n >> 4;
  const int tile = ntiles - 1 - (int)blockIdx.x;
  const int qb = tile << 4;

  bf16x8 qf[8];
  const unsigned short* qp = Q + (size_t)(qb + c) * DIM;
#pragma unroll
  for (int kc = 0; kc < 8; ++kc)
    qf[kc] = *(const bf16x8*)(qp + kc * 32 + g * 8);

  f32x4 o[16];
#pragma unroll
  for (int t = 0; t < 16; ++t) o[t] = (f32x4){0.f, 0.f, 0.f, 0.f};
  float m_r[4] = {-1e30f, -1e30f, -1e30f, -1e30f};
  float l_r[4] = {0.f, 0.f, 0.f, 0.f};

  const int nchunk = ((qb + 14) >> 5) + 1;
  for (int kt = wave; kt < nchunk; kt += 8) {
    const int k0 = kt << 5;
    f32x4 s0 = {0.f, 0.f, 0.f, 0.f}, s1 = {0.f, 0.f, 0.f, 0.f};
    const unsigned short* kp0 = K + (size_t)(k0 + c) * DIM;
    const unsigned short* kp1 = K + (size_t)(k0 + 16 + c) * DIM;
#pragma unroll
    for (int kc = 0; kc < 8; ++kc) {
      bf16x8 kb0 = *(const bf16x8*)(kp0 + kc * 32 + g * 8);
      bf16x8 kb1 = *(const bf16x8*)(kp1 + kc * 32 + g * 8);
      s0 = __builtin_amdgcn_mfma_f32_16x16x32_bf16(qf[kc], kb0, s0, 0, 0, 0);
      s1 = __builtin_amdgcn_mfma_f32_16x16x32_bf16(qf[kc], kb1, s1, 0, 0, 0);
    }
    if (k0 + 31 >= qb) {
#pragma unroll
      for (int r = 0; r < 4; ++r) {
        const int qrow = qb + 4 * g + r;
        if (k0 + c >= qrow)      s0[r] = -1e9f;
        if (k0 + 16 + c >= qrow) s1[r] = -1e9f;
      }
    }
    f32x4 p0, p1;
    float alpha[4];
#pragma unroll
    for (int r = 0; r < 4; ++r) {
      float mx = fmaxf(s0[r], s1[r]);
      mx = fmaxf(mx, __shfl_xor(mx, 1, 64));
      mx = fmaxf(mx, __shfl_xor(mx, 2, 64));
      mx = fmaxf(mx, __shfl_xor(mx, 4, 64));
      mx = fmaxf(mx, __shfl_xor(mx, 8, 64));
      const float mn = fmaxf(m_r[r], mx);
      const float a = __expf(m_r[r] - mn);
      p0[r] = __expf(s0[r] - mn);
      p1[r] = __expf(s1[r] - mn);
      float ls = p0[r] + p1[r];
      ls += __shfl_xor(ls, 1, 64);
      ls += __shfl_xor(ls, 2, 64);
      ls += __shfl_xor(ls, 4, 64);
      ls += __shfl_xor(ls, 8, 64);
      l_r[r] = l_r[r] * a + ls;
      m_r[r] = mn;
      alpha[r] = a;
    }
#pragma unroll
    for (int t = 0; t < 16; ++t) {
      o[t][0] *= alpha[0]; o[t][1] *= alpha[1];
      o[t][2] *= alpha[2]; o[t][3] *= alpha[3];
    }
#pragma unroll
    for (int r = 0; r < 4; ++r) {
      plds[wave][4 * g + r][c]      = f2bf(p0[r]);
      plds[wave][4 * g + r][16 + c] = f2bf(p1[r]);
    }
    asm volatile("s_waitcnt lgkmcnt(0)" ::: "memory");
    const bf16x8 pa = *(const bf16x8*)(&plds[wave][c][8 * g]);
    const unsigned short* vp = Vt + (size_t)c * n + k0 + 8 * g;
#pragma unroll
    for (int t = 0; t < 16; ++t) {
      bf16x8 vb = *(const bf16x8*)(vp + (size_t)(t * 16) * n);
      o[t] = __builtin_amdgcn_mfma_f32_16x16x32_bf16(pa, vb, o[t], 0, 0, 0);
    }
  }

  auto write_slot = [&](int s) {
#pragma unroll
    for (int r = 0; r < 4; ++r) {
      const int row = 4 * g + r;
#pragma unroll
      for (int t = 0; t < 16; ++t) so[s][row][t * 16 + c] = o[t][r];
      if (c == 0) { sml[s][0][row] = m_r[r]; sml[s][1][row] = l_r[r]; }
    }
  };
  auto merge_slot = [&](int s) {
    float aa[4], ab[4];
#pragma unroll
    for (int r = 0; r < 4; ++r) {
      const int row = 4 * g + r;
      const float mb = sml[s][0][row], lb = sml[s][1][row];
      const float ms = fmaxf(m_r[r], mb);
      aa[r] = __expf(m_r[r] - ms);
      ab[r] = __expf(mb - ms);
      l_r[r] = l_r[r] * aa[r] + lb * ab[r];
      m_r[r] = ms;
    }
#pragma unroll
    for (int t = 0; t < 16; ++t)
#pragma unroll
      for (int r = 0; r < 4; ++r)
        o[t][r] = o[t][r] * aa[r] + so[s][4 * g + r][t * 16 + c] * ab[r];
  };

  __syncthreads();
  if (wave >= 4) write_slot(wave - 4);
  __syncthreads();
  if (wave < 4) merge_slot(wave);
  __syncthreads();
  if (wave == 2 || wave == 3) write_slot(wave - 2);
  __syncthreads();
  if (wave < 2) merge_slot(wave);
  __syncthreads();
  if (wave == 1) write_slot(0);
  __syncthreads();
  if (wave == 0) {
    merge_slot(0);
#pragma unroll
    for (int r = 0; r < 4; ++r) {
      const int qrow = qb + 4 * g + r;
      if (qrow == 0) continue;
      const float inv = 1.0f / l_r[r];
#pragma unroll
      for (int t = 0; t < 16; ++t)
        out[(size_t)qrow * DIM + t * 16 + c] = o[t][r] * inv;
    }
  }
}

// ---- main flash: 128-row tiles, 8 waves x 16 rows; proportional key-splits;
// static-max softmax p = exp(s - 16); K swizzled, V XOR-granule swizzled
// (74 KB LDS -> 2 blocks/CU); heaviest slot first; bf16 partials ----
__global__ __launch_bounds__(512, 4) void k_flash4(const unsigned short* __restrict__ Q,
    const unsigned short* __restrict__ K, const unsigned short* __restrict__ Vt,
    unsigned short* __restrict__ po, float* __restrict__ pl, int n, int shift) {
  __shared__ unsigned short KL[2 * 32 * 256];      // swizzled K chunks (32 KB)
  __shared__ unsigned short VL[2 * 256 * 32];      // XOR-swizzled V chunks (32 KB)
  __shared__ unsigned short plds[8][16][40];       // P transpose (10 KB)

  const int wave = threadIdx.x >> 6;
  const int lane = threadIdx.x & 63;
  const int g = lane >> 4;
  const int c = lane & 15;
  const int T = n >> 7;

  auto cum = [&](int t) {
    const int a = t >> shift;
    return t + ((a * (a - 1)) << (shift - 1)) + a * (t & ((1 << shift) - 1));
  };
  const int bid = (int)(gridDim.x - 1 - blockIdx.x);   // heaviest slots first
  int t = (int)sqrtf((float)bid * (float)(1 << (shift + 1)) + 1.0f);
  if (t > T - 1) t = T - 1;
  while (cum(t) > bid) --t;
  while (t + 1 < T && cum(t + 1) <= bid) ++t;
  const int sp = bid - cum(t);
  const int nsplit = (t >> shift) + 1;
  const int qb = t << 7;
  const int qw = qb + (wave << 4);
  const int nch = 4 * t + 4;

  // Q fragments (pre-scaled by 1/16)
  bf16x8 qf[8];
  const unsigned short* qp = Q + (size_t)(qw + c) * DIM;
#pragma unroll
  for (int kc = 0; kc < 8; ++kc)
    qf[kc] = *(const bf16x8*)(qp + kc * 32 + g * 8);

  f32x4 o[16];
#pragma unroll
  for (int i = 0; i < 16; ++i) o[i] = (f32x4){0.f, 0.f, 0.f, 0.f};
  float lac[4] = {0.f, 0.f, 0.f, 0.f};

  // staging roles: waves 0-3 -> K (swizzled), waves 4-7 -> V (XOR-granule)
  const bool kRole = (wave < 4);
  const int kr0  = (wave << 3) + (lane >> 5);          // K row base (+2/load)
  const int kgw  = lane & 31;                          // K granule col
  const int vd0  = ((wave - 4) << 6) + (lane >> 2);    // V d base (+16/load)
  const int vk8  = (lane & 3) << 3;                    // V logical short col
  const int vwg  = (lane & 3) ^ ((lane >> 3) & 3);     // V phys granule (write)
  const int vrg  = ((c >> 1) & 3);                     // V granule XOR (read)

  i32x4 stg[4];
  auto load_stg = [&](int k0) {
    if (kRole) {
#pragma unroll
      for (int i = 0; i < 4; ++i)
        stg[i] = *(const i32x4*)(K + (size_t)(k0 + kr0 + 2 * i) * DIM + kgw * 8);
    } else {
#pragma unroll
      for (int i = 0; i < 4; ++i)
        stg[i] = *(const i32x4*)(Vt + (size_t)(vd0 + 16 * i) * n + k0 + vk8);
    }
  };
  auto write_stg = [&](int buf) {
    if (kRole) {
#pragma unroll
      for (int i = 0; i < 4; ++i) {
        const int row = kr0 + 2 * i;
        *(i32x4*)(&KL[(buf << 13) + (row << 8) + ((kgw ^ (row & 7)) << 3)]) = stg[i];
      }
    } else {
#pragma unroll
      for (int i = 0; i < 4; ++i)
        *(i32x4*)(&VL[(buf << 13) + ((vd0 + 16 * i) << 5) + (vwg << 3)]) = stg[i];
    }
  };

  int ci = sp;
  load_stg(ci << 5);
  write_stg(0);
  __syncthreads();
  int buf = 0;
  for (;;) {
    const int k0 = ci << 5;
    const int cin = ci + nsplit;
    const bool more = (cin < nch);
    if (more) load_stg(cin << 5);

    if (k0 <= qw + 14) {
      f32x4 s0 = {0.f, 0.f, 0.f, 0.f}, s1 = {0.f, 0.f, 0.f, 0.f};
      const int bb = buf << 13;
      const int r0 = c, r1 = 16 + c;
      __builtin_amdgcn_s_setprio(1);
#pragma unroll
      for (int kc = 0; kc < 8; ++kc) {
        bf16x8 kb0 = *(const bf16x8*)(&KL[bb + (r0 << 8) + (((kc * 4 + g) ^ (r0 & 7)) << 3)]);
        bf16x8 kb1 = *(const bf16x8*)(&KL[bb + (r1 << 8) + (((kc * 4 + g) ^ (r1 & 7)) << 3)]);
        s0 = __builtin_amdgcn_mfma_f32_16x16x32_bf16(qf[kc], kb0, s0, 0, 0, 0);
        s1 = __builtin_amdgcn_mfma_f32_16x16x32_bf16(qf[kc], kb1, s1, 0, 0, 0);
      }
      __builtin_amdgcn_s_setprio(0);
      if (k0 + 31 >= qw) {   // causal: j >= i masked (-1e9, exp -> exact 0)
#pragma unroll
        for (int r = 0; r < 4; ++r) {
          const int qrow = qw + 4 * g + r;
          if (k0 + c >= qrow)      s0[r] = -1e9f;
          if (k0 + 16 + c >= qrow) s1[r] = -1e9f;
        }
      }
      // static-max softmax: p = exp(s - 16), softmax shift-invariant
      f32x4 p0, p1;
#pragma unroll
      for (int r = 0; r < 4; ++r) {
        p0[r] = __expf(s0[r] - 16.f);
        p1[r] = __expf(s1[r] - 16.f);
        lac[r] += p0[r] + p1[r];
      }
#pragma unroll
      for (int r = 0; r < 4; ++r) {
        plds[wave][4 * g + r][c]      = f2bf(p0[r]);
        plds[wave][4 * g + r][16 + c] = f2bf(p1[r]);
      }
      asm volatile("s_waitcnt lgkmcnt(0)" ::: "memory");
      const bf16x8 pa = *(const bf16x8*)(&plds[wave][c][8 * g]);
      __builtin_amdgcn_s_setprio(1);
#pragma unroll
      for (int i = 0; i < 16; ++i) {
        bf16x8 vb = *(const bf16x8*)(&VL[bb + ((c + 16 * i) << 5) + ((g ^ vrg) << 3)]);
        o[i] = __builtin_amdgcn_mfma_f32_16x16x32_bf16(pa, vb, o[i], 0, 0, 0);
      }
      __builtin_amdgcn_s_setprio(0);
    }

    if (more) write_stg(buf ^ 1);
    __syncthreads();
    if (!more) break;
    buf ^= 1;
    ci = cin;
  }

  // epilogue: reduce l over the 16 key-lanes, write bf16 o-partials + fp32 l
  unsigned short* pow = po + ((size_t)bid * 128 + (wave << 4)) * DIM;
  float* plw = pl + (size_t)bid * 128 + (wave << 4);
#pragma unroll
  for (int r = 0; r < 4; ++r) {
    float ls = lac[r];
    ls += __shfl_xor(ls, 1, 64);
    ls += __shfl_xor(ls, 2, 64);
    ls += __shfl_xor(ls, 4, 64);
    ls += __shfl_xor(ls, 8, 64);
    const int row = 4 * g + r;
    if (c == 0) plw[row] = ls;
#pragma unroll
    for (int i = 0; i < 16; ++i)
      pow[(size_t)row * DIM + i * 16 + c] = f2bf(o[i][r]);
  }
}

// ---- combine: straight sum over a tile's splits (common static max),
// normalize; block 0 additionally rewrites row 0 exactly ----
__global__ __launch_bounds__(256) void k_comb(const unsigned short* __restrict__ po,
    const float* __restrict__ pl, const float* __restrict__ partial,
    const float* __restrict__ Wv, float* __restrict__ out, int n, int shift) {
  const int row = blockIdx.x * 16 + (threadIdx.x >> 4);
  const int c0 = (threadIdx.x & 15) * 16;
  const int t = row >> 7;
  const int a = t >> shift;
  const int cumt = t + ((a * (a - 1)) << (shift - 1)) + a * (t & ((1 << shift) - 1));
  const int ns = a + 1;
  const int lr = row & 127;

  float acc[16];
#pragma unroll
  for (int j = 0; j < 16; ++j) acc[j] = 0.f;
  float lsum = 0.f;
  for (int s = 0; s < ns; ++s) {
    lsum += pl[(size_t)(cumt + s) * 128 + lr];
    const unsigned short* pp = po + ((size_t)(cumt + s) * 128 + lr) * DIM + c0;
    bf16x8 v0 = *(const bf16x8*)(pp);
    bf16x8 v1 = *(const bf16x8*)(pp + 8);
#pragma unroll
    for (int j = 0; j < 8; ++j) {
      union { float f; uint32_t u; } cv0, cv1;
      cv0.u = ((uint32_t)(unsigned short)v0[j]) << 16;
      cv1.u = ((uint32_t)(unsigned short)v1[j]) << 16;
      acc[j]     += cv0.f;
      acc[8 + j] += cv1.f;
    }
  }
  const float inv = (lsum > 0.f) ? 1.0f / lsum : 0.f;
#pragma unroll
  for (int j = 0; j < 16; ++j)
    out[(size_t)row * DIM + c0 + j] = acc[j] * inv;

  if (blockIdx.x == 0) {   // exact row 0: mean(x) @ Wv
    __shared__ float xm[DIM];
    const int tid = threadIdx.x;
    float s = 0.f;
    const int nb = n / 128;
    for (int b = 0; b < nb; ++b) s += partial[b * DIM + tid];
    xm[tid] = s / (float)n;
    __syncthreads();
    float oo = 0.f;
    for (int k = 0; k < DIM; ++k) oo += xm[k] * Wv[k * DIM + tid];
    out[tid] = oo;
  }
}

extern "C" void kernel_launch(void* const* d_in, const int* in_sizes, int n_in,
                              void* d_out, int out_size, void* d_ws, size_t ws_size,
                              hipStream_t stream) {
  const float* x  = (const float*)d_in[0];
  const float* Wq = (const float*)d_in[1];
  const float* Wk = (const float*)d_in[2];
  const float* Wv = (const float*)d_in[3];
  float* out = (float*)d_out;
  const int n = in_sizes[0] / DIM;
  const int T = n >> 7;

  char* ws = (char*)d_ws;
  const size_t wt_bytes  = (size_t)3 * DIM * DIM * 2;
  const size_t mat_bytes = (size_t)n * DIM * 2;
  const size_t par_bytes = (size_t)(n / 128) * DIM * 4;
  const size_t base = wt_bytes + 3 * mat_bytes + par_bytes;

  unsigned short* Wt = (unsigned short*)(ws);
  unsigned short* Q  = (unsigned short*)(ws + wt_bytes);
  unsigned short* K  = (unsigned short*)(ws + wt_bytes + mat_bytes);
  unsigned short* Vt = (unsigned short*)(ws + wt_bytes + 2 * mat_bytes);
  float* partial     = (float*)(ws + wt_bytes + 3 * mat_bytes);

  int shift = 2, nslots = 0;
  bool ok = false;
  for (shift = 2; shift <= 6; ++shift) {
    const int a = T >> shift, b2 = T & ((1 << shift) - 1);
    nslots = T + ((a * (a - 1)) << (shift - 1)) + a * b2;
    const size_t need = base + (size_t)nslots * 128 * 4
                             + (size_t)nslots * 128 * DIM * 2;
    if (ws_size >= need) { ok = true; break; }
  }
  float* pl          = (float*)(ws + base);
  unsigned short* po = (unsigned short*)(ws + base + (size_t)nslots * 128 * 4);

  hipLaunchKernelGGL(k_misc, dim3(48 + n / 128), dim3(256), 0, stream,
                     Wq, Wk, Wv, Wt, x, partial, n);
  hipLaunchKernelGGL(k_proj, dim3(n / 64, 3), dim3(256), 0, stream, x, Wt, Q, K, Vt, n);
  if (ok) {
    hipLaunchKernelGGL(k_flash4, dim3(nslots), dim3(512), 0, stream,
                       Q, K, Vt, po, pl, n, shift);
    hipLaunchKernelGGL(k_comb, dim3(n / 16), dim3(256), 0, stream,
                       po, pl, partial, Wv, out, n, shift);
  } else {
    hipLaunchKernelGGL(k_flash2, dim3(n / 16), dim3(512), 0, stream, Q, K, Vt, out, n);
    hipLaunchKernelGGL(k_meanB, dim3(1), dim3(256), 0, stream, partial, Wv, out, n);
  }
}

// Round 6
// 151.498 us; speedup vs baseline: 1.9441x; 1.9441x over previous
//
#include <hip/hip_runtime.h>
#include <hip/hip_bf16.h>
#include <stdint.h>

#define DIM 256

typedef float f32x4 __attribute__((ext_vector_type(4)));
typedef short bf16x8 __attribute__((ext_vector_type(8)));
typedef short bf16x4 __attribute__((ext_vector_type(4)));
typedef int   i32x4 __attribute__((ext_vector_type(4)));

__device__ __forceinline__ unsigned short f2bf(float f) {
  union { float f; uint32_t u; } v; v.f = f;
  uint32_t u = v.u;
  u += 0x7FFFu + ((u >> 16) & 1u);   // round-to-nearest-even
  return (unsigned short)(u >> 16);
}

// ---- fused: W transpose/cast (blocks 0..47) + x column partial sums ----
__global__ __launch_bounds__(256) void k_misc(const float* __restrict__ Wq,
    const float* __restrict__ Wk, const float* __restrict__ Wv,
    unsigned short* __restrict__ Wt, const float* __restrict__ x,
    float* __restrict__ partial, int n) {
  if (blockIdx.x < 48) {
    const int w = blockIdx.x >> 4;
    const int nb = blockIdx.x & 15;
    const float* W = (w == 0) ? Wq : (w == 1) ? Wk : Wv;
    unsigned short* dst = Wt + w * DIM * DIM;
    const int row = nb * 16 + (threadIdx.x >> 4);
    const int k0 = (threadIdx.x & 15) * 16;
    for (int k = 0; k < 16; ++k)
      dst[row * DIM + k0 + k] = f2bf(W[(k0 + k) * DIM + row]);
  } else {
    const int b = blockIdx.x - 48, tid = threadIdx.x;
    float acc = 0.f;
    const float* xp = x + (size_t)b * 128 * DIM + tid;
    for (int r = 0; r < 128; ++r) acc += xp[r * DIM];
    partial[b * DIM + tid] = acc;
  }
}

// ---- projections: Q = (x@Wq)/16, K = x@Wk, Vt = (x@Wv)^T, all bf16 ----
__global__ __launch_bounds__(256) void k_proj(const float* __restrict__ x,
    const unsigned short* __restrict__ Wt, unsigned short* __restrict__ Q,
    unsigned short* __restrict__ K, unsigned short* __restrict__ Vt, int n) {
  const int rb = blockIdx.x * 64;
  const int w = blockIdx.y;
  const int wave = threadIdx.x >> 6;
  const int lane = threadIdx.x & 63;
  const int g = lane >> 4;
  const int c = lane & 15;
  const int row0 = rb + wave * 16;

  bf16x8 af[8];
  const float* xp = x + (size_t)(row0 + c) * DIM;
#pragma unroll
  for (int kc = 0; kc < 8; ++kc) {
    f32x4 a0 = *(const f32x4*)(xp + kc * 32 + g * 8);
    f32x4 a1 = *(const f32x4*)(xp + kc * 32 + g * 8 + 4);
    bf16x8 a;
    a[0] = (short)f2bf(a0[0]); a[1] = (short)f2bf(a0[1]);
    a[2] = (short)f2bf(a0[2]); a[3] = (short)f2bf(a0[3]);
    a[4] = (short)f2bf(a1[0]); a[5] = (short)f2bf(a1[1]);
    a[6] = (short)f2bf(a1[2]); a[7] = (short)f2bf(a1[3]);
    af[kc] = a;
  }
  const unsigned short* Wb = Wt + w * DIM * DIM;
  f32x4 acc[16];
#pragma unroll
  for (int t = 0; t < 16; ++t) acc[t] = (f32x4){0.f, 0.f, 0.f, 0.f};
#pragma unroll
  for (int nt = 0; nt < 16; ++nt) {
#pragma unroll
    for (int kc = 0; kc < 8; ++kc) {
      bf16x8 b = *(const bf16x8*)(Wb + (nt * 16 + c) * DIM + kc * 32 + g * 8);
      acc[nt] = __builtin_amdgcn_mfma_f32_16x16x32_bf16(af[kc], b, acc[nt], 0, 0, 0);
    }
  }
  if (w == 2) {
    // Vt: pack 4 consecutive rows (4g..4g+3) into one 8B store per nt
#pragma unroll
    for (int nt = 0; nt < 16; ++nt) {
      const int col = nt * 16 + c;
      bf16x4 pv;
      pv[0] = (short)f2bf(acc[nt][0]); pv[1] = (short)f2bf(acc[nt][1]);
      pv[2] = (short)f2bf(acc[nt][2]); pv[3] = (short)f2bf(acc[nt][3]);
      *(bf16x4*)(Vt + (size_t)col * n + row0 + 4 * g) = pv;
    }
  } else {
#pragma unroll
    for (int nt = 0; nt < 16; ++nt) {
#pragma unroll
      for (int r = 0; r < 4; ++r) {
        const int row = row0 + 4 * g + r;
        const int col = nt * 16 + c;
        const float v = acc[nt][r];
        if (w == 0) Q[(size_t)row * DIM + col] = f2bf(v * 0.0625f);
        else        K[(size_t)row * DIM + col] = f2bf(v);
      }
    }
  }
}

// ---- row 0 exact path for fallback: out[0] = mean_n(x) @ Wv ----
__global__ void k_meanB(const float* __restrict__ partial, const float* __restrict__ Wv,
                        float* __restrict__ out, int n) {
  __shared__ float xm[DIM];
  const int tid = threadIdx.x;
  float acc = 0.f;
  const int nb = n / 128;
  for (int b = 0; b < nb; ++b) acc += partial[b * DIM + tid];
  xm[tid] = acc / (float)n;
  __syncthreads();
  float o = 0.f;
  for (int k = 0; k < DIM; ++k) o += xm[k] * Wv[k * DIM + tid];
  out[tid] = o;
}

// ---- fallback flash (round-2): 8 waves key-split one 16-row tile ----
__global__ __launch_bounds__(512, 4) void k_flash2(const unsigned short* __restrict__ Q,
    const unsigned short* __restrict__ K, const unsigned short* __restrict__ Vt,
    float* __restrict__ out, int n) {
  __shared__ float so[4][16][257];
  __shared__ float sml[4][2][16];
  __shared__ unsigned short plds[8][16][40];

  const int wave = threadIdx.x >> 6;
  const int lane = threadIdx.x & 63;
  const int g = lane >> 4;
  const int c = lane & 15;
  const int ntiles = n >> 4;
  const int tile = ntiles - 1 - (int)blockIdx.x;
  const int qb = tile << 4;

  bf16x8 qf[8];
  const unsigned short* qp = Q + (size_t)(qb + c) * DIM;
#pragma unroll
  for (int kc = 0; kc < 8; ++kc)
    qf[kc] = *(const bf16x8*)(qp + kc * 32 + g * 8);

  f32x4 o[16];
#pragma unroll
  for (int t = 0; t < 16; ++t) o[t] = (f32x4){0.f, 0.f, 0.f, 0.f};
  float m_r[4] = {-1e30f, -1e30f, -1e30f, -1e30f};
  float l_r[4] = {0.f, 0.f, 0.f, 0.f};

  const int nchunk = ((qb + 14) >> 5) + 1;
  for (int kt = wave; kt < nchunk; kt += 8) {
    const int k0 = kt << 5;
    f32x4 s0 = {0.f, 0.f, 0.f, 0.f}, s1 = {0.f, 0.f, 0.f, 0.f};
    const unsigned short* kp0 = K + (size_t)(k0 + c) * DIM;
    const unsigned short* kp1 = K + (size_t)(k0 + 16 + c) * DIM;
#pragma unroll
    for (int kc = 0; kc < 8; ++kc) {
      bf16x8 kb0 = *(const bf16x8*)(kp0 + kc * 32 + g * 8);
      bf16x8 kb1 = *(const bf16x8*)(kp1 + kc * 32 + g * 8);
      s0 = __builtin_amdgcn_mfma_f32_16x16x32_bf16(qf[kc], kb0, s0, 0, 0, 0);
      s1 = __builtin_amdgcn_mfma_f32_16x16x32_bf16(qf[kc], kb1, s1, 0, 0, 0);
    }
    if (k0 + 31 >= qb) {
#pragma unroll
      for (int r = 0; r < 4; ++r) {
        const int qrow = qb + 4 * g + r;
        if (k0 + c >= qrow)      s0[r] = -1e9f;
        if (k0 + 16 + c >= qrow) s1[r] = -1e9f;
      }
    }
    f32x4 p0, p1;
    float alpha[4];
#pragma unroll
    for (int r = 0; r < 4; ++r) {
      float mx = fmaxf(s0[r], s1[r]);
      mx = fmaxf(mx, __shfl_xor(mx, 1, 64));
      mx = fmaxf(mx, __shfl_xor(mx, 2, 64));
      mx = fmaxf(mx, __shfl_xor(mx, 4, 64));
      mx = fmaxf(mx, __shfl_xor(mx, 8, 64));
      const float mn = fmaxf(m_r[r], mx);
      const float a = __expf(m_r[r] - mn);
      p0[r] = __expf(s0[r] - mn);
      p1[r] = __expf(s1[r] - mn);
      float ls = p0[r] + p1[r];
      ls += __shfl_xor(ls, 1, 64);
      ls += __shfl_xor(ls, 2, 64);
      ls += __shfl_xor(ls, 4, 64);
      ls += __shfl_xor(ls, 8, 64);
      l_r[r] = l_r[r] * a + ls;
      m_r[r] = mn;
      alpha[r] = a;
    }
#pragma unroll
    for (int t = 0; t < 16; ++t) {
      o[t][0] *= alpha[0]; o[t][1] *= alpha[1];
      o[t][2] *= alpha[2]; o[t][3] *= alpha[3];
    }
#pragma unroll
    for (int r = 0; r < 4; ++r) {
      plds[wave][4 * g + r][c]      = f2bf(p0[r]);
      plds[wave][4 * g + r][16 + c] = f2bf(p1[r]);
    }
    asm volatile("s_waitcnt lgkmcnt(0)" ::: "memory");
    const bf16x8 pa = *(const bf16x8*)(&plds[wave][c][8 * g]);
    const unsigned short* vp = Vt + (size_t)c * n + k0 + 8 * g;
#pragma unroll
    for (int t = 0; t < 16; ++t) {
      bf16x8 vb = *(const bf16x8*)(vp + (size_t)(t * 16) * n);
      o[t] = __builtin_amdgcn_mfma_f32_16x16x32_bf16(pa, vb, o[t], 0, 0, 0);
    }
  }

  auto write_slot = [&](int s) {
#pragma unroll
    for (int r = 0; r < 4; ++r) {
      const int row = 4 * g + r;
#pragma unroll
      for (int t = 0; t < 16; ++t) so[s][row][t * 16 + c] = o[t][r];
      if (c == 0) { sml[s][0][row] = m_r[r]; sml[s][1][row] = l_r[r]; }
    }
  };
  auto merge_slot = [&](int s) {
    float aa[4], ab[4];
#pragma unroll
    for (int r = 0; r < 4; ++r) {
      const int row = 4 * g + r;
      const float mb = sml[s][0][row], lb = sml[s][1][row];
      const float ms = fmaxf(m_r[r], mb);
      aa[r] = __expf(m_r[r] - ms);
      ab[r] = __expf(mb - ms);
      l_r[r] = l_r[r] * aa[r] + lb * ab[r];
      m_r[r] = ms;
    }
#pragma unroll
    for (int t = 0; t < 16; ++t)
#pragma unroll
      for (int r = 0; r < 4; ++r)
        o[t][r] = o[t][r] * aa[r] + so[s][4 * g + r][t * 16 + c] * ab[r];
  };

  __syncthreads();
  if (wave >= 4) write_slot(wave - 4);
  __syncthreads();
  if (wave < 4) merge_slot(wave);
  __syncthreads();
  if (wave == 2 || wave == 3) write_slot(wave - 2);
  __syncthreads();
  if (wave < 2) merge_slot(wave);
  __syncthreads();
  if (wave == 1) write_slot(0);
  __syncthreads();
  if (wave == 0) {
    merge_slot(0);
#pragma unroll
    for (int r = 0; r < 4; ++r) {
      const int qrow = qb + 4 * g + r;
      if (qrow == 0) continue;
      const float inv = 1.0f / l_r[r];
#pragma unroll
      for (int t = 0; t < 16; ++t)
        out[(size_t)qrow * DIM + t * 16 + c] = o[t][r] * inv;
    }
  }
}

// ---- main flash: 128-row tiles, 8 waves x 16 rows; proportional key-splits;
// static-max softmax p = exp(s - 16); K swizzled, V XOR-granule swizzled
// (74 KB LDS -> 2 blocks/CU); launch_bounds(512,2): VGPR<=128 so NO spill
// (round 5's (512,4) forced VGPR=64 -> 411 MB scratch traffic) ----
__global__ __launch_bounds__(512, 2) void k_flash4(const unsigned short* __restrict__ Q,
    const unsigned short* __restrict__ K, const unsigned short* __restrict__ Vt,
    unsigned short* __restrict__ po, float* __restrict__ pl, int n, int shift) {
  __shared__ unsigned short KL[2 * 32 * 256];      // swizzled K chunks (32 KB)
  __shared__ unsigned short VL[2 * 256 * 32];      // XOR-swizzled V chunks (32 KB)
  __shared__ unsigned short plds[8][16][40];       // P transpose (10 KB)

  const int wave = threadIdx.x >> 6;
  const int lane = threadIdx.x & 63;
  const int g = lane >> 4;
  const int c = lane & 15;
  const int T = n >> 7;

  auto cum = [&](int t) {
    const int a = t >> shift;
    return t + ((a * (a - 1)) << (shift - 1)) + a * (t & ((1 << shift) - 1));
  };
  const int bid = (int)(gridDim.x - 1 - blockIdx.x);   // heaviest slots first
  int t = (int)sqrtf((float)bid * (float)(1 << (shift + 1)) + 1.0f);
  if (t > T - 1) t = T - 1;
  while (cum(t) > bid) --t;
  while (t + 1 < T && cum(t + 1) <= bid) ++t;
  const int sp = bid - cum(t);
  const int nsplit = (t >> shift) + 1;
  const int qb = t << 7;
  const int qw = qb + (wave << 4);
  const int nch = 4 * t + 4;

  // Q fragments (pre-scaled by 1/16)
  bf16x8 qf[8];
  const unsigned short* qp = Q + (size_t)(qw + c) * DIM;
#pragma unroll
  for (int kc = 0; kc < 8; ++kc)
    qf[kc] = *(const bf16x8*)(qp + kc * 32 + g * 8);

  f32x4 o[16];
#pragma unroll
  for (int i = 0; i < 16; ++i) o[i] = (f32x4){0.f, 0.f, 0.f, 0.f};
  float lac[4] = {0.f, 0.f, 0.f, 0.f};

  // staging roles: waves 0-3 -> K (swizzled), waves 4-7 -> V (XOR-granule)
  const bool kRole = (wave < 4);
  const int kr0  = (wave << 3) + (lane >> 5);          // K row base (+2/load)
  const int kgw  = lane & 31;                          // K granule col
  const int vd0  = ((wave - 4) << 6) + (lane >> 2);    // V d base (+16/load)
  const int vk8  = (lane & 3) << 3;                    // V logical short col
  const int vwg  = (lane & 3) ^ ((lane >> 3) & 3);     // V phys granule (write)
  const int vrg  = ((c >> 1) & 3);                     // V granule XOR (read)

  i32x4 stg[4];
  auto load_stg = [&](int k0) {
    if (kRole) {
#pragma unroll
      for (int i = 0; i < 4; ++i)
        stg[i] = *(const i32x4*)(K + (size_t)(k0 + kr0 + 2 * i) * DIM + kgw * 8);
    } else {
#pragma unroll
      for (int i = 0; i < 4; ++i)
        stg[i] = *(const i32x4*)(Vt + (size_t)(vd0 + 16 * i) * n + k0 + vk8);
    }
  };
  auto write_stg = [&](int buf) {
    if (kRole) {
#pragma unroll
      for (int i = 0; i < 4; ++i) {
        const int row = kr0 + 2 * i;
        *(i32x4*)(&KL[(buf << 13) + (row << 8) + ((kgw ^ (row & 7)) << 3)]) = stg[i];
      }
    } else {
#pragma unroll
      for (int i = 0; i < 4; ++i)
        *(i32x4*)(&VL[(buf << 13) + ((vd0 + 16 * i) << 5) + (vwg << 3)]) = stg[i];
    }
  };

  int ci = sp;
  load_stg(ci << 5);
  write_stg(0);
  __syncthreads();
  int buf = 0;
  for (;;) {
    const int k0 = ci << 5;
    const int cin = ci + nsplit;
    const bool more = (cin < nch);
    if (more) load_stg(cin << 5);

    if (k0 <= qw + 14) {
      f32x4 s0 = {0.f, 0.f, 0.f, 0.f}, s1 = {0.f, 0.f, 0.f, 0.f};
      const int bb = buf << 13;
      const int r0 = c, r1 = 16 + c;
      __builtin_amdgcn_s_setprio(1);
#pragma unroll
      for (int kc = 0; kc < 8; ++kc) {
        bf16x8 kb0 = *(const bf16x8*)(&KL[bb + (r0 << 8) + (((kc * 4 + g) ^ (r0 & 7)) << 3)]);
        bf16x8 kb1 = *(const bf16x8*)(&KL[bb + (r1 << 8) + (((kc * 4 + g) ^ (r1 & 7)) << 3)]);
        s0 = __builtin_amdgcn_mfma_f32_16x16x32_bf16(qf[kc], kb0, s0, 0, 0, 0);
        s1 = __builtin_amdgcn_mfma_f32_16x16x32_bf16(qf[kc], kb1, s1, 0, 0, 0);
      }
      __builtin_amdgcn_s_setprio(0);
      if (k0 + 31 >= qw) {   // causal: j >= i masked (-1e9, exp -> exact 0)
#pragma unroll
        for (int r = 0; r < 4; ++r) {
          const int qrow = qw + 4 * g + r;
          if (k0 + c >= qrow)      s0[r] = -1e9f;
          if (k0 + 16 + c >= qrow) s1[r] = -1e9f;
        }
      }
      // static-max softmax: p = exp(s - 16), softmax shift-invariant
      f32x4 p0, p1;
#pragma unroll
      for (int r = 0; r < 4; ++r) {
        p0[r] = __expf(s0[r] - 16.f);
        p1[r] = __expf(s1[r] - 16.f);
        lac[r] += p0[r] + p1[r];
      }
#pragma unroll
      for (int r = 0; r < 4; ++r) {
        plds[wave][4 * g + r][c]      = f2bf(p0[r]);
        plds[wave][4 * g + r][16 + c] = f2bf(p1[r]);
      }
      asm volatile("s_waitcnt lgkmcnt(0)" ::: "memory");
      const bf16x8 pa = *(const bf16x8*)(&plds[wave][c][8 * g]);
      __builtin_amdgcn_s_setprio(1);
#pragma unroll
      for (int i = 0; i < 16; ++i) {
        bf16x8 vb = *(const bf16x8*)(&VL[bb + ((c + 16 * i) << 5) + ((g ^ vrg) << 3)]);
        o[i] = __builtin_amdgcn_mfma_f32_16x16x32_bf16(pa, vb, o[i], 0, 0, 0);
      }
      __builtin_amdgcn_s_setprio(0);
    }

    if (more) write_stg(buf ^ 1);
    __syncthreads();
    if (!more) break;
    buf ^= 1;
    ci = cin;
  }

  // epilogue: reduce l over the 16 key-lanes, write bf16 o-partials + fp32 l
  unsigned short* pow = po + ((size_t)bid * 128 + (wave << 4)) * DIM;
  float* plw = pl + (size_t)bid * 128 + (wave << 4);
#pragma unroll
  for (int r = 0; r < 4; ++r) {
    float ls = lac[r];
    ls += __shfl_xor(ls, 1, 64);
    ls += __shfl_xor(ls, 2, 64);
    ls += __shfl_xor(ls, 4, 64);
    ls += __shfl_xor(ls, 8, 64);
    const int row = 4 * g + r;
    if (c == 0) plw[row] = ls;
#pragma unroll
    for (int i = 0; i < 16; ++i)
      pow[(size_t)row * DIM + i * 16 + c] = f2bf(o[i][r]);
  }
}

// ---- combine: straight sum over a tile's splits (common static max),
// normalize; block 0 additionally rewrites row 0 exactly ----
__global__ __launch_bounds__(256) void k_comb(const unsigned short* __restrict__ po,
    const float* __restrict__ pl, const float* __restrict__ partial,
    const float* __restrict__ Wv, float* __restrict__ out, int n, int shift) {
  const int row = blockIdx.x * 16 + (threadIdx.x >> 4);
  const int c0 = (threadIdx.x & 15) * 16;
  const int t = row >> 7;
  const int a = t >> shift;
  const int cumt = t + ((a * (a - 1)) << (shift - 1)) + a * (t & ((1 << shift) - 1));
  const int ns = a + 1;
  const int lr = row & 127;

  float acc[16];
#pragma unroll
  for (int j = 0; j < 16; ++j) acc[j] = 0.f;
  float lsum = 0.f;
  for (int s = 0; s < ns; ++s) {
    lsum += pl[(size_t)(cumt + s) * 128 + lr];
    const unsigned short* pp = po + ((size_t)(cumt + s) * 128 + lr) * DIM + c0;
    bf16x8 v0 = *(const bf16x8*)(pp);
    bf16x8 v1 = *(const bf16x8*)(pp + 8);
#pragma unroll
    for (int j = 0; j < 8; ++j) {
      union { float f; uint32_t u; } cv0, cv1;
      cv0.u = ((uint32_t)(unsigned short)v0[j]) << 16;
      cv1.u = ((uint32_t)(unsigned short)v1[j]) << 16;
      acc[j]     += cv0.f;
      acc[8 + j] += cv1.f;
    }
  }
  const float inv = (lsum > 0.f) ? 1.0f / lsum : 0.f;
#pragma unroll
  for (int j = 0; j < 16; ++j)
    out[(size_t)row * DIM + c0 + j] = acc[j] * inv;

  if (blockIdx.x == 0) {   // exact row 0: mean(x) @ Wv
    __shared__ float xm[DIM];
    const int tid = threadIdx.x;
    float s = 0.f;
    const int nb = n / 128;
    for (int b = 0; b < nb; ++b) s += partial[b * DIM + tid];
    xm[tid] = s / (float)n;
    __syncthreads();
    float oo = 0.f;
    for (int k = 0; k < DIM; ++k) oo += xm[k] * Wv[k * DIM + tid];
    out[tid] = oo;
  }
}

extern "C" void kernel_launch(void* const* d_in, const int* in_sizes, int n_in,
                              void* d_out, int out_size, void* d_ws, size_t ws_size,
                              hipStream_t stream) {
  const float* x  = (const float*)d_in[0];
  const float* Wq = (const float*)d_in[1];
  const float* Wk = (const float*)d_in[2];
  const float* Wv = (const float*)d_in[3];
  float* out = (float*)d_out;
  const int n = in_sizes[0] / DIM;
  const int T = n >> 7;

  char* ws = (char*)d_ws;
  const size_t wt_bytes  = (size_t)3 * DIM * DIM * 2;
  const size_t mat_bytes = (size_t)n * DIM * 2;
  const size_t par_bytes = (size_t)(n / 128) * DIM * 4;
  const size_t base = wt_bytes + 3 * mat_bytes + par_bytes;

  unsigned short* Wt = (unsigned short*)(ws);
  unsigned short* Q  = (unsigned short*)(ws + wt_bytes);
  unsigned short* K  = (unsigned short*)(ws + wt_bytes + mat_bytes);
  unsigned short* Vt = (unsigned short*)(ws + wt_bytes + 2 * mat_bytes);
  float* partial     = (float*)(ws + wt_bytes + 3 * mat_bytes);

  int shift = 2, nslots = 0;
  bool ok = false;
  for (shift = 2; shift <= 6; ++shift) {
    const int a = T >> shift, b2 = T & ((1 << shift) - 1);
    nslots = T + ((a * (a - 1)) << (shift - 1)) + a * b2;
    const size_t need = base + (size_t)nslots * 128 * 4
                             + (size_t)nslots * 128 * DIM * 2;
    if (ws_size >= need) { ok = true; break; }
  }
  float* pl          = (float*)(ws + base);
  unsigned short* po = (unsigned short*)(ws + base + (size_t)nslots * 128 * 4);

  hipLaunchKernelGGL(k_misc, dim3(48 + n / 128), dim3(256), 0, stream,
                     Wq, Wk, Wv, Wt, x, partial, n);
  hipLaunchKernelGGL(k_proj, dim3(n / 64, 3), dim3(256), 0, stream, x, Wt, Q, K, Vt, n);
  if (ok) {
    hipLaunchKernelGGL(k_flash4, dim3(nslots), dim3(512), 0, stream,
                       Q, K, Vt, po, pl, n, shift);
    hipLaunchKernelGGL(k_comb, dim3(n / 16), dim3(256), 0, stream,
                       po, pl, partial, Wv, out, n, shift);
  } else {
    hipLaunchKernelGGL(k_flash2, dim3(n / 16), dim3(512), 0, stream, Q, K, Vt, out, n);
    hipLaunchKernelGGL(k_meanB, dim3(1), dim3(256), 0, stream, partial, Wv, out, n);
  }
}